// Round 11
// baseline (154.080 us; speedup 1.0000x reference)
//
#include <hip/hip_runtime.h>
#include <math.h>

#define CLAMPV 1000000.0f
#define PI_F     3.14159274f
#define HALFPI_F 1.57079633f
#define LN2_F    0.69314718f      // ln2
#define L2E_F    1.44269504f      // 1/ln2
#define C1_F     0.17328680f      // ln2/4      : exp2-arg coeff, complex nodes (log2 of |.|^2)
#define C2_F     0.05515890f      // ln2/(4*pi) : rev-arg coeff, complex nodes
#define C2R_F    0.11031780f      // ln2/(2*pi) : rev-arg coeff, real-child nodes

typedef float v2f __attribute__((ext_vector_type(2)));

__device__ __forceinline__ v2f vb(float s) { return (v2f){s, s}; }
__device__ __forceinline__ v2f vfma(v2f a, v2f b, v2f c) { return __builtin_elementwise_fma(a, b, c); }

// Wave-uniform gate pointer -> s_load on the scalar pipe.
__device__ __forceinline__ const float* gptr(const float* __restrict__ g, int node) {
    return g + 6 * __builtin_amdgcn_readfirstlane(node);
}

// monotone float -> sortable uint ; bin = top 12 bits
__device__ __forceinline__ unsigned sortkey(float x) {
    unsigned u = __float_as_uint(x);
    u ^= (unsigned)(((int)u) >> 31) | 0x80000000u;
    return u;
}

// # set bits of m below this lane
__device__ __forceinline__ unsigned rank_below(unsigned long long m) {
    return __builtin_amdgcn_mbcnt_hi((unsigned)(m >> 32),
           __builtin_amdgcn_mbcnt_lo((unsigned)m, 0u));
}

// ---------------- pass-1: branch-free real-positive evaluation + taint ----------------
// One tree node assuming real children. tmin tracks min over all nodes of
// min(u,v); element needs the exact pass iff tmin <= 0 (or NaN).
__device__ __forceinline__ v2f fnode(v2f l, v2f r, v2f x,
                                     const float* __restrict__ g, v2f& tmin) {
    float g0 = g[0], g1 = g[1], g2 = g[2], g3 = g[3], g4 = g[4], g5 = g[5];
    v2f u = vfma(vb(g2), l, vfma(vb(g1), x, vb(g0)));
    v2f v = vfma(vb(g5), r, vfma(vb(g4), x, vb(g3)));
    tmin = __builtin_elementwise_min(tmin, __builtin_elementwise_min(u, v));
    v2f L2u = (v2f){__builtin_amdgcn_logf(u.x), __builtin_amdgcn_logf(u.y)};
    v2f L2v = (v2f){__builtin_amdgcn_logf(v.x), __builtin_amdgcn_logf(v.y)};
    v2f e = (vb(LN2_F) * L2u) * L2v;
    v2f rr = (v2f){__builtin_amdgcn_exp2f(e.x), __builtin_amdgcn_exp2f(e.y)};
    return __builtin_elementwise_min(rr, vb(CLAMPV));   // +inf -> 1e6; r >= 0
}

// two independent packed chains sharing the gate scalars (ILP-2)
struct P { v2f a, b; };
__device__ __forceinline__ P fnode2(P l, P r, v2f xa, v2f xb,
                                    const float* __restrict__ g,
                                    v2f& tma, v2f& tmb) {
    P o;
    o.a = fnode(l.a, r.a, xa, g, tma);
    o.b = fnode(l.b, r.b, xb, g, tmb);
    return o;
}
__device__ __forceinline__ P leaf2(float aa, float bb, v2f xa, v2f xb) {
    P o; o.a = vfma(vb(bb), xa, vb(aa)); o.b = vfma(vb(bb), xb, vb(aa)); return o;
}

// Block: 64 lanes x 16 subtrees. Each lane owns FOUR elements as two packed
// chains: A = {e0, e0+64}, B = {e0+128, e0+192}, e0 = blk*256 + lane.
// Grid 256 blocks = 1/CU, 4 waves/SIMD, ILP-2 in-thread. Branch-free.
__global__ __launch_bounds__(1024, 4) void eml_fast_taint(
    const float* __restrict__ x_g, const float* __restrict__ leaf_g,
    const float* __restrict__ gate_g, float* __restrict__ out,
    unsigned* __restrict__ cnt, unsigned* __restrict__ hist,
    unsigned* __restrict__ list, int batch, int out_real_only)
{
    __shared__ float4 sA[16][64];   // (root0, root1, tmin0, tmin1) chain A
    __shared__ float4 sB[16][64];   // chain B

    const int lane = threadIdx.x;    // 0..63
    const int s    = threadIdx.y;    // subtree 0..15
    const int e0 = blockIdx.x * 256 + lane;
    const v2f xa = (v2f){x_g[e0],       x_g[e0 + 64]};
    const v2f xb = (v2f){x_g[e0 + 128], x_g[e0 + 192]};

    v2f tma = vb(1.0f), tmb = vb(1.0f);
    P cA, cB, root;

#pragma clang loop unroll(disable)
    for (int q = 0; q < 4; ++q) {
        const int jq = 64 * s + 16 * q;
        P r2[2], h1, c;
#pragma unroll
        for (int p = 0; p < 4; ++p) {
            const int j = jq + 4 * p;
            const float* L = leaf_g + 2 * __builtin_amdgcn_readfirstlane(j);
            P l0 = leaf2(L[0], L[1], xa, xb);
            P l1 = leaf2(L[2], L[3], xa, xb);
            P l2 = leaf2(L[4], L[5], xa, xb);
            P l3 = leaf2(L[6], L[7], xa, xb);

            P A  = fnode2(l0, l1, xa, xb, gptr(gate_g, j >> 1), tma, tmb);
            P B  = fnode2(l2, l3, xa, xb, gptr(gate_g, (j >> 1) + 1), tma, tmb);
            P r1 = fnode2(A, B, xa, xb, gptr(gate_g, 512 + (j >> 2)), tma, tmb);
            if (p & 1) r2[p >> 1] = fnode2(h1, r1, xa, xb, gptr(gate_g, 768 + (j >> 3)), tma, tmb);
            else       h1 = r1;
        }
        c = fnode2(r2[0], r2[1], xa, xb, gptr(gate_g, 896 + (jq >> 4)), tma, tmb);
        if      (q == 0) cA = c;
        else if (q == 1) cB = fnode2(cA, c, xa, xb, gptr(gate_g, 960 + 2 * s), tma, tmb);
        else if (q == 2) cA = c;
        else {
            P t  = fnode2(cA, c, xa, xb, gptr(gate_g, 961 + 2 * s), tma, tmb);
            root = fnode2(cB, t, xa, xb, gptr(gate_g, 992 + s), tma, tmb);
        }
    }

    sA[s][lane] = make_float4(root.a.x, root.a.y, tma.x, tma.y);
    sB[s][lane] = make_float4(root.b.x, root.b.y, tmb.x, tmb.y);
    __syncthreads();
    if (s != 0) return;

    // tail rounds 6..9 (wave0 only), both chains, carrying tmin through
#pragma clang loop unroll(disable)
    for (int L = 6; L <= 9; ++L) {
        const int cntL = 1 << (9 - L);
        const int base = 1024 - (1 << (10 - L));
#pragma clang loop unroll(disable)
        for (int j = 0; j < cntL; ++j) {
            const float* g = gptr(gate_g, base + j);
            float4 a0 = sA[2 * j][lane], a1 = sA[2 * j + 1][lane];
            v2f ta = __builtin_elementwise_min((v2f){a0.z, a0.w}, (v2f){a1.z, a1.w});
            v2f ra = fnode((v2f){a0.x, a0.y}, (v2f){a1.x, a1.y}, xa, g, ta);
            sA[j][lane] = make_float4(ra.x, ra.y, ta.x, ta.y);

            float4 b0 = sB[2 * j][lane], b1 = sB[2 * j + 1][lane];
            v2f tb = __builtin_elementwise_min((v2f){b0.z, b0.w}, (v2f){b1.z, b1.w});
            v2f rb = fnode((v2f){b0.x, b0.y}, (v2f){b1.x, b1.y}, xb, g, tb);
            sB[j][lane] = make_float4(rb.x, rb.y, tb.x, tb.y);
        }
    }

    float4 fa = sA[0][lane], fb = sB[0][lane];
    const bool t0 = !(fa.z > 0.0f);   // taint iff tmin <= 0 or NaN
    const bool t1 = !(fa.w > 0.0f);
    const bool t2 = !(fb.z > 0.0f);
    const bool t3 = !(fb.w > 0.0f);

    // untainted: final value is real positive, imag = +0 (exact)
    if (out_real_only) {
        if (!t0) out[e0]       = fa.x;
        if (!t1) out[e0 + 64]  = fa.y;
        if (!t2) out[e0 + 128] = fb.x;
        if (!t3) out[e0 + 192] = fb.y;
    } else {
        float2* o2 = reinterpret_cast<float2*>(out);
        if (!t0) o2[e0]       = make_float2(fa.x, 0.0f);
        if (!t1) o2[e0 + 64]  = make_float2(fa.y, 0.0f);
        if (!t2) o2[e0 + 128] = make_float2(fb.x, 0.0f);
        if (!t3) o2[e0 + 192] = make_float2(fb.y, 0.0f);
    }

    // compact tainted ids + build 4096-bin global histogram (uncontended)
    unsigned long long m0 = __ballot(t0), m1 = __ballot(t1);
    unsigned long long m2 = __ballot(t2), m3 = __ballot(t3);
    int n0 = __popcll(m0), n1 = __popcll(m1), n2 = __popcll(m2), n3 = __popcll(m3);
    unsigned base = 0;
    int tot = n0 + n1 + n2 + n3;
    if (lane == 0 && tot) base = atomicAdd(cnt, (unsigned)tot);
    base = __shfl(base, 0);
    if (t0) { list[base + rank_below(m0)] = (unsigned)e0;
              atomicAdd(&hist[sortkey(xa.x) >> 20], 1u); }
    if (t1) { list[base + n0 + rank_below(m1)] = (unsigned)(e0 + 64);
              atomicAdd(&hist[sortkey(xa.y) >> 20], 1u); }
    if (t2) { list[base + n0 + n1 + rank_below(m2)] = (unsigned)(e0 + 128);
              atomicAdd(&hist[sortkey(xb.x) >> 20], 1u); }
    if (t3) { list[base + n0 + n1 + n2 + rank_below(m3)] = (unsigned)(e0 + 192);
              atomicAdd(&hist[sortkey(xb.y) >> 20], 1u); }
}

// ---------------- scan: 4096-bin exclusive prefix (1 block, tiny) ----------------
__global__ __launch_bounds__(1024) void eml_scan(
    const unsigned* __restrict__ hist, unsigned* __restrict__ offs)
{
    __shared__ unsigned part[1024];
    const int t = threadIdx.x;
    unsigned h0 = hist[4*t], h1 = hist[4*t+1], h2 = hist[4*t+2], h3 = hist[4*t+3];
    unsigned sum = h0 + h1 + h2 + h3;
    part[t] = sum;
    __syncthreads();
    for (int d = 1; d < 1024; d <<= 1) {
        unsigned v = (t >= d) ? part[t - d] : 0u;
        __syncthreads();
        part[t] += v;
        __syncthreads();
    }
    unsigned excl = part[t] - sum;
    offs[4*t]   = excl;
    offs[4*t+1] = excl + h0;
    offs[4*t+2] = excl + h0 + h1;
    offs[4*t+3] = excl + h0 + h1 + h2;
}

// ---------------- scatter: multi-block, atomics spread over 4096 bins ----------------
__global__ __launch_bounds__(256) void eml_scatter(
    const float* __restrict__ x_g, const unsigned* __restrict__ cnt,
    const unsigned* __restrict__ list, unsigned* __restrict__ offs,
    unsigned* __restrict__ list2)
{
    const unsigned n = cnt[0];
    const unsigned i = blockIdx.x * 256u + threadIdx.x;
    if (i < n) {
        unsigned id = list[i];
        unsigned pos = atomicAdd(&offs[sortkey(x_g[id]) >> 20], 1u);
        list2[pos] = id;
    }
}

// ---------------- pass-2: exact kernel over the (sorted) tainted list ----------------

__device__ __forceinline__ v2f sanitv(v2f v) {
    v2f c;
    c.x = __builtin_amdgcn_fmed3f(v.x, -CLAMPV, CLAMPV);
    c.y = __builtin_amdgcn_fmed3f(v.y, -CLAMPV, CLAMPV);
    c.x = (v.x != v.x) ? 0.0f : c.x;
    c.y = (v.y != v.y) ? 0.0f : c.y;
    return c;
}

__device__ __forceinline__ v2f fatan2v(v2f y, v2f x) {
    v2f ax = __builtin_elementwise_abs(x);
    v2f ay = __builtin_elementwise_abs(y);
    v2f mx = __builtin_elementwise_max(ax, ay);
    v2f mn = __builtin_elementwise_min(ax, ay);
    v2f r  = (v2f){__builtin_amdgcn_rcpf(mx.x), __builtin_amdgcn_rcpf(mx.y)};
    v2f t  = mn * r;
    v2f z  = t * t;
    v2f p  = vfma(z, vfma(z, vfma(z, vfma(z,
             vb(0.02083510f), vb(-0.08513300f)), vb(0.18014100f)), vb(-0.33029950f)),
             vb(0.99986600f));
    p = p * t;
    p.x = (ay.x > ax.x) ? (HALFPI_F - p.x) : p.x;
    p.y = (ay.y > ax.y) ? (HALFPI_F - p.y) : p.y;
    p.x = (x.x < 0.0f) ? (PI_F - p.x) : p.x;
    p.y = (x.y < 0.0f) ? (PI_F - p.y) : p.y;
    p.x = copysignf(p.x, y.x);
    p.y = copysignf(p.y, y.y);
    return p;
}

__device__ __forceinline__ void exp_tailv(v2f e, v2f f0, v2f& ore, v2f& oim) {
    v2f r = (v2f){__builtin_amdgcn_exp2f(e.x), __builtin_amdgcn_exp2f(e.y)};
    v2f f = (v2f){__builtin_amdgcn_fractf(f0.x), __builtin_amdgcn_fractf(f0.y)};
    v2f sn = (v2f){__builtin_amdgcn_sinf(f.x), __builtin_amdgcn_sinf(f.y)};
    v2f cs = (v2f){__builtin_amdgcn_cosf(f.x), __builtin_amdgcn_cosf(f.y)};
    ore = sanitv(r * cs);
    oim = sanitv(r * sn);
}

__device__ __forceinline__ void fast_rp(v2f ure, v2f vre, v2f& ore, v2f& oim) {
    v2f L2u = (v2f){__builtin_amdgcn_logf(ure.x), __builtin_amdgcn_logf(ure.y)};
    v2f L2v = (v2f){__builtin_amdgcn_logf(vre.x), __builtin_amdgcn_logf(vre.y)};
    v2f e = (vb(LN2_F) * L2u) * L2v;
    v2f r = (v2f){__builtin_amdgcn_exp2f(e.x), __builtin_amdgcn_exp2f(e.y)};
    v2f c = __builtin_elementwise_min(r, vb(CLAMPV));
    c.x = (r.x != r.x) ? 0.0f : c.x;
    c.y = (r.y != r.y) ? 0.0f : c.y;
    ore = c;
    oim = vb(0.0f);
}

__device__ __forceinline__ void node_any(
    v2f lre, v2f lim, v2f rre, v2f rim,
    v2f x, const float* __restrict__ g,
    v2f& ore, v2f& oim)
{
    float g0 = g[0], g1 = g[1], g2 = g[2], g3 = g[3], g4 = g[4], g5 = g[5];
    v2f ure = vfma(vb(g2), lre, vfma(vb(g1), x, vb(g0)));
    v2f vre = vfma(vb(g5), rre, vfma(vb(g4), x, vb(g3)));
    v2f mn = __builtin_elementwise_min(ure, vre);

    unsigned long long bad =
        __ballot(lim.x != 0.0f) | __ballot(lim.y != 0.0f) |
        __ballot(rim.x != 0.0f) | __ballot(rim.y != 0.0f) |
        __ballot(mn.x <= 0.0f)  | __ballot(mn.y <= 0.0f);

    if (bad == 0ULL) {
        fast_rp(ure, vre, ore, oim);
    } else {
        // exact complex path; fma(g2, lim, +0) forces -0 -> +0 (load-bearing
        // for the atan2 branch choice when a child's imag is exactly zero)
        v2f uim = vfma(vb(g2), lim, vb(0.0f));
        v2f vim = vfma(vb(g5), rim, vb(0.0f));

        v2f nu = vfma(ure, ure, uim * uim);
        v2f nv = vfma(vre, vre, vim * vim);
        v2f L2u = (v2f){__builtin_amdgcn_logf(nu.x), __builtin_amdgcn_logf(nu.y)};
        v2f L2v = (v2f){__builtin_amdgcn_logf(nv.x), __builtin_amdgcn_logf(nv.y)};
        v2f Au = fatan2v(uim, ure);
        v2f Av = fatan2v(vim, vre);

        v2f t2 = vb(L2E_F) * (Au * Av);
        v2f e  = vfma(vb(C1_F) * L2u, L2v, -t2);
        v2f s2 = vfma(L2u, Av, Au * L2v);
        v2f f0 = vb(C2_F) * s2;
        exp_tailv(e, f0, ore, oim);
    }
}

__device__ __forceinline__ void node_r0(
    v2f l, v2f r, v2f x, const float* __restrict__ g,
    v2f& ore, v2f& oim)
{
    float g0 = g[0], g1 = g[1], g2 = g[2], g3 = g[3], g4 = g[4], g5 = g[5];
    v2f u = vfma(vb(g2), l, vfma(vb(g1), x, vb(g0)));
    v2f v = vfma(vb(g5), r, vfma(vb(g4), x, vb(g3)));
    v2f mn = __builtin_elementwise_min(u, v);

    unsigned long long bad = __ballot(mn.x <= 0.0f) | __ballot(mn.y <= 0.0f);

    if (bad == 0ULL) {
        fast_rp(u, v, ore, oim);
    } else {
        v2f au = __builtin_elementwise_abs(u);
        v2f av = __builtin_elementwise_abs(v);
        v2f L2u = (v2f){__builtin_amdgcn_logf(au.x), __builtin_amdgcn_logf(au.y)};
        v2f L2v = (v2f){__builtin_amdgcn_logf(av.x), __builtin_amdgcn_logf(av.y)};
        v2f Au, Av;
        Au.x = (u.x < 0.0f) ? PI_F : 0.0f;
        Au.y = (u.y < 0.0f) ? PI_F : 0.0f;
        Av.x = (v.x < 0.0f) ? PI_F : 0.0f;
        Av.y = (v.y < 0.0f) ? PI_F : 0.0f;

        v2f t2 = vb(L2E_F) * (Au * Av);
        v2f e  = vfma(vb(LN2_F) * L2u, L2v, -t2);
        v2f s2 = vfma(L2u, Av, Au * L2v);
        v2f f0 = vb(C2R_F) * s2;
        exp_tailv(e, f0, ore, oim);
    }
}

__global__ __launch_bounds__(1024, 8) void eml_slow(
    const float* __restrict__ x_g, const float* __restrict__ leaf_g,
    const float* __restrict__ gate_g, const unsigned* __restrict__ cnt,
    const unsigned* __restrict__ list, float* __restrict__ out,
    int batch, int out_real_only)
{
    __shared__ float4 s_t[16][64];

    const unsigned count = cnt[0];
    const unsigned r0 = blockIdx.x * 128u;
    if (r0 >= count) return;

    const int lane = threadIdx.x;
    const int s    = threadIdx.y;
    const unsigned ra = min(r0 + (unsigned)lane, count - 1u);
    const unsigned rb = min(r0 + (unsigned)lane + 64u, count - 1u);
    const unsigned ia = list[ra], ib = list[rb];
    const v2f x2 = (v2f){x_g[ia], x_g[ib]};

    v2f cAre, cAim, cBre, cBim, rootre, rootim;

#pragma clang loop unroll(disable)
    for (int q = 0; q < 4; ++q) {
        const int jq = 64 * s + 16 * q;
        v2f r2re[2], r2im[2];
        v2f h1re = vb(0.0f), h1im = vb(0.0f);
        v2f cre, cim;

#pragma unroll
        for (int p = 0; p < 4; ++p) {
            const int j = jq + 4 * p;
            const float* L = leaf_g + 2 * __builtin_amdgcn_readfirstlane(j);
            v2f l0 = vfma(vb(L[1]), x2, vb(L[0]));
            v2f l1 = vfma(vb(L[3]), x2, vb(L[2]));
            v2f l2 = vfma(vb(L[5]), x2, vb(L[4]));
            v2f l3 = vfma(vb(L[7]), x2, vb(L[6]));

            v2f Are, Aim, Bre, Bim;
            node_r0(l0, l1, x2, gptr(gate_g, j >> 1), Are, Aim);
            node_r0(l2, l3, x2, gptr(gate_g, (j >> 1) + 1), Bre, Bim);

            v2f r1re, r1im;
            node_any(Are, Aim, Bre, Bim, x2, gptr(gate_g, 512 + (j >> 2)), r1re, r1im);

            if (p & 1) {
                node_any(h1re, h1im, r1re, r1im, x2,
                         gptr(gate_g, 768 + (j >> 3)), r2re[p >> 1], r2im[p >> 1]);
            } else {
                h1re = r1re; h1im = r1im;
            }
        }
        node_any(r2re[0], r2im[0], r2re[1], r2im[1], x2,
                 gptr(gate_g, 896 + (jq >> 4)), cre, cim);

        if (q == 0) {
            cAre = cre; cAim = cim;
        } else if (q == 1) {
            node_any(cAre, cAim, cre, cim, x2, gptr(gate_g, 960 + 2 * s), cBre, cBim);
        } else if (q == 2) {
            cAre = cre; cAim = cim;
        } else {
            v2f tre, tim;
            node_any(cAre, cAim, cre, cim, x2, gptr(gate_g, 961 + 2 * s), tre, tim);
            node_any(cBre, cBim, tre, tim, x2, gptr(gate_g, 992 + s), rootre, rootim);
        }
    }

    s_t[s][lane] = make_float4(rootre.x, rootre.y, rootim.x, rootim.y);
    __syncthreads();
    if (s != 0) return;

#pragma clang loop unroll(disable)
    for (int L = 6; L <= 9; ++L) {
        const int cntL = 1 << (9 - L);
        const int base = 1024 - (1 << (10 - L));
#pragma clang loop unroll(disable)
        for (int j = 0; j < cntL; ++j) {
            float4 a = s_t[2 * j][lane], b = s_t[2 * j + 1][lane];
            v2f rre, rim;
            node_any((v2f){a.x, a.y}, (v2f){a.z, a.w},
                     (v2f){b.x, b.y}, (v2f){b.z, b.w},
                     x2, gptr(gate_g, base + j), rre, rim);
            s_t[j][lane] = make_float4(rre.x, rre.y, rim.x, rim.y);
        }
    }

    float4 fin = s_t[0][lane];
    if (out_real_only) {
        out[ia] = fin.x;
        out[ib] = fin.y;
    } else {
        reinterpret_cast<float2*>(out)[ia] = make_float2(fin.x, fin.z);
        reinterpret_cast<float2*>(out)[ib] = make_float2(fin.y, fin.w);
    }
}

extern "C" void kernel_launch(void* const* d_in, const int* in_sizes, int n_in,
                              void* d_out, int out_size, void* d_ws, size_t ws_size,
                              hipStream_t stream) {
    const float* x    = (const float*)d_in[0];
    const float* leaf = (const float*)d_in[1];
    const float* gate = (const float*)d_in[2];
    float* out = (float*)d_out;
    const int batch = in_sizes[0];

    const int out_real_only = (out_size == batch) ? 1 : 0;

    // ws layout: cnt(pad 64) | hist[4096] | offs[4096] | list[batch] | list2[batch]
    unsigned* cnt   = (unsigned*)d_ws;
    unsigned* hist  = cnt + 64;
    unsigned* offs  = hist + 4096;
    unsigned* list  = offs + 4096;
    unsigned* list2 = list + batch;
    const size_t need_full = (64 + 4096 + 4096 + 2 * (size_t)batch) * sizeof(unsigned);
    const bool do_sort = (ws_size >= need_full);

    // zero cnt + hist in one async memset (16640 B)
    hipMemsetAsync(cnt, 0, (64 + 4096) * sizeof(unsigned), stream);

    dim3 block(64, 16);
    hipLaunchKernelGGL(eml_fast_taint, dim3(batch / 256), block, 0, stream,
                       x, leaf, gate, out, cnt, hist, list, batch, out_real_only);
    if (do_sort) {
        hipLaunchKernelGGL(eml_scan, dim3(1), dim3(1024), 0, stream, hist, offs);
        hipLaunchKernelGGL(eml_scatter, dim3((batch + 255) / 256), dim3(256), 0, stream,
                           x, cnt, list, offs, list2);
    }
    hipLaunchKernelGGL(eml_slow, dim3(batch / 128), block, 0, stream,
                       x, leaf, gate, cnt,
                       do_sort ? list2 : list, out, batch, out_real_only);
}

// Round 12
// 110.543 us; speedup vs baseline: 1.3939x; 1.3939x over previous
//
#include <hip/hip_runtime.h>
#include <math.h>

#define CLAMPV 1000000.0f
#define PI_F     3.14159274f
#define HALFPI_F 1.57079633f
#define LN2_F    0.69314718f      // ln2
#define L2E_F    1.44269504f      // 1/ln2
#define C1_F     0.17328680f      // ln2/4      : exp2-arg coeff, complex nodes (log2 of |.|^2)
#define C2_F     0.05515890f      // ln2/(4*pi) : rev-arg coeff, complex nodes
#define C2R_F    0.11031780f      // ln2/(2*pi) : rev-arg coeff, real-child nodes

typedef float v2f __attribute__((ext_vector_type(2)));

__device__ __forceinline__ v2f vb(float s) { return (v2f){s, s}; }
__device__ __forceinline__ v2f vfma(v2f a, v2f b, v2f c) { return __builtin_elementwise_fma(a, b, c); }

// Wave-uniform gate pointer -> s_load on the scalar pipe.
__device__ __forceinline__ const float* gptr(const float* __restrict__ g, int node) {
    return g + 6 * __builtin_amdgcn_readfirstlane(node);
}

// sanitize: nan -> 0, clamp to [-1e6,1e6] (med3 absorbs +-inf)
__device__ __forceinline__ v2f sanitv(v2f v) {
    v2f c;
    c.x = __builtin_amdgcn_fmed3f(v.x, -CLAMPV, CLAMPV);
    c.y = __builtin_amdgcn_fmed3f(v.y, -CLAMPV, CLAMPV);
    c.x = (v.x != v.x) ? 0.0f : c.x;
    c.y = (v.y != v.y) ? 0.0f : c.y;
    return c;
}

// packed fast atan2, deg-9 minimax; (+0, x<0) -> +pi matches numpy for the
// exact-zero-imag chains (imag forced to +0 upstream).
__device__ __forceinline__ v2f fatan2v(v2f y, v2f x) {
    v2f ax = __builtin_elementwise_abs(x);
    v2f ay = __builtin_elementwise_abs(y);
    v2f mx = __builtin_elementwise_max(ax, ay);
    v2f mn = __builtin_elementwise_min(ax, ay);
    v2f r  = (v2f){__builtin_amdgcn_rcpf(mx.x), __builtin_amdgcn_rcpf(mx.y)};
    v2f t  = mn * r;
    v2f z  = t * t;
    v2f p  = vfma(z, vfma(z, vfma(z, vfma(z,
             vb(0.02083510f), vb(-0.08513300f)), vb(0.18014100f)), vb(-0.33029950f)),
             vb(0.99986600f));
    p = p * t;
    p.x = (ay.x > ax.x) ? (HALFPI_F - p.x) : p.x;
    p.y = (ay.y > ax.y) ? (HALFPI_F - p.y) : p.y;
    p.x = (x.x < 0.0f) ? (PI_F - p.x) : p.x;
    p.y = (x.y < 0.0f) ? (PI_F - p.y) : p.y;
    p.x = copysignf(p.x, y.x);
    p.y = copysignf(p.y, y.y);
    return p;
}

// exp2/sin/cos tail from pre-folded args: r = 2^e ; angle = f0 revolutions.
__device__ __forceinline__ void exp_tailv(v2f e, v2f f0, v2f& ore, v2f& oim) {
    v2f r = (v2f){__builtin_amdgcn_exp2f(e.x), __builtin_amdgcn_exp2f(e.y)};
    v2f f = (v2f){__builtin_amdgcn_fractf(f0.x), __builtin_amdgcn_fractf(f0.y)};
    v2f sn = (v2f){__builtin_amdgcn_sinf(f.x), __builtin_amdgcn_sinf(f.y)};
    v2f cs = (v2f){__builtin_amdgcn_cosf(f.x), __builtin_amdgcn_cosf(f.y)};
    ore = sanitv(r * cs);
    oim = sanitv(r * sn);
}

// Real-positive fast path body: children real, u > 0, v > 0 across the wave.
//   out = ( min(2^(ln2*log2(u)*log2(v)), 1e6), +0 )
__device__ __forceinline__ void fast_rp(v2f ure, v2f vre, v2f& ore, v2f& oim) {
    v2f L2u = (v2f){__builtin_amdgcn_logf(ure.x), __builtin_amdgcn_logf(ure.y)};
    v2f L2v = (v2f){__builtin_amdgcn_logf(vre.x), __builtin_amdgcn_logf(vre.y)};
    v2f e = (vb(LN2_F) * L2u) * L2v;
    v2f r = (v2f){__builtin_amdgcn_exp2f(e.x), __builtin_amdgcn_exp2f(e.y)};
    v2f c = __builtin_elementwise_min(r, vb(CLAMPV));
    c.x = (r.x != r.x) ? 0.0f : c.x;
    c.y = (r.y != r.y) ? 0.0f : c.y;
    ore = c;
    oim = vb(0.0f);
}

// General node (children may be complex). Wave-uniform fast path when every
// lane has real children and strictly positive u, v; otherwise exact complex.
__device__ __forceinline__ void node_any(
    v2f lre, v2f lim, v2f rre, v2f rim,
    v2f x, const float* __restrict__ g,
    v2f& ore, v2f& oim)
{
    float g0 = g[0], g1 = g[1], g2 = g[2], g3 = g[3], g4 = g[4], g5 = g[5];
    v2f ure = vfma(vb(g2), lre, vfma(vb(g1), x, vb(g0)));
    v2f vre = vfma(vb(g5), rre, vfma(vb(g4), x, vb(g3)));
    v2f mn = __builtin_elementwise_min(ure, vre);

    unsigned long long bad =
        __ballot(lim.x != 0.0f) | __ballot(lim.y != 0.0f) |
        __ballot(rim.x != 0.0f) | __ballot(rim.y != 0.0f) |
        __ballot(mn.x <= 0.0f)  | __ballot(mn.y <= 0.0f);

    if (bad == 0ULL) {
        fast_rp(ure, vre, ore, oim);
    } else {
        // exact complex path; fma(g2, lim, +0) forces -0 -> +0 (load-bearing
        // for the atan2 branch choice when a child's imag is exactly zero)
        v2f uim = vfma(vb(g2), lim, vb(0.0f));
        v2f vim = vfma(vb(g5), rim, vb(0.0f));

        v2f nu = vfma(ure, ure, uim * uim);
        v2f nv = vfma(vre, vre, vim * vim);
        v2f L2u = (v2f){__builtin_amdgcn_logf(nu.x), __builtin_amdgcn_logf(nu.y)};
        v2f L2v = (v2f){__builtin_amdgcn_logf(nv.x), __builtin_amdgcn_logf(nv.y)};
        v2f Au = fatan2v(uim, ure);
        v2f Av = fatan2v(vim, vre);

        v2f t2 = vb(L2E_F) * (Au * Av);
        v2f e  = vfma(vb(C1_F) * L2u, L2v, -t2);
        v2f s2 = vfma(L2u, Av, Au * L2v);
        v2f f0 = vb(C2_F) * s2;
        exp_tailv(e, f0, ore, oim);
    }
}

// Round-0 node: children are real leaf values.
__device__ __forceinline__ void node_r0(
    v2f l, v2f r, v2f x, const float* __restrict__ g,
    v2f& ore, v2f& oim)
{
    float g0 = g[0], g1 = g[1], g2 = g[2], g3 = g[3], g4 = g[4], g5 = g[5];
    v2f u = vfma(vb(g2), l, vfma(vb(g1), x, vb(g0)));
    v2f v = vfma(vb(g5), r, vfma(vb(g4), x, vb(g3)));
    v2f mn = __builtin_elementwise_min(u, v);

    unsigned long long bad = __ballot(mn.x <= 0.0f) | __ballot(mn.y <= 0.0f);

    if (bad == 0ULL) {
        fast_rp(u, v, ore, oim);
    } else {
        v2f au = __builtin_elementwise_abs(u);
        v2f av = __builtin_elementwise_abs(v);
        v2f L2u = (v2f){__builtin_amdgcn_logf(au.x), __builtin_amdgcn_logf(au.y)};
        v2f L2v = (v2f){__builtin_amdgcn_logf(av.x), __builtin_amdgcn_logf(av.y)};
        v2f Au, Av;
        Au.x = (u.x < 0.0f) ? PI_F : 0.0f;
        Au.y = (u.y < 0.0f) ? PI_F : 0.0f;
        Av.x = (v.x < 0.0f) ? PI_F : 0.0f;
        Av.y = (v.y < 0.0f) ? PI_F : 0.0f;

        v2f t2 = vb(L2E_F) * (Au * Av);
        v2f e  = vfma(vb(LN2_F) * L2u, L2v, -t2);
        v2f s2 = vfma(L2u, Av, Au * L2v);
        v2f f0 = vb(C2R_F) * s2;
        exp_tailv(e, f0, ore, oim);
    }
}

// Block: 64 lanes x 16 subtrees (1024 threads = 16 waves). Each lane owns 2
// batch elements (e0 = blk*128 + lane, e1 = e0 + 64), math 2-wide packed.
// Per thread: 64-leaf subtree, rounds 0-5 in registers (static merge).
// Tail rounds 6-9 PARALLELIZED across waves (8/4/2/1) with barriers — removes
// the wave0 serial tail that stretched the makespan in the R7 variant.
__global__ __launch_bounds__(1024, 8) void EMLTree1DLinear_kernel(
    const float* __restrict__ x_g,      // [batch]
    const float* __restrict__ leaf_g,   // [1024][2]
    const float* __restrict__ gate_g,   // [1023][2][3] flat
    float* __restrict__ out,            // [batch][2] interleaved complex (or [batch] real)
    int batch, int out_real_only)
{
    __shared__ float4 s_t[30][64];        // 30720 B: rows 0..15 round-5 roots,
                                          // 16..23 r6, 24..27 r7, 28..29 r8
    const int lane = threadIdx.x;         // 0..63
    const int s    = threadIdx.y;         // subtree, 0..15

    const int e0 = blockIdx.x * 128 + lane;
    const v2f x2 = (v2f){x_g[e0], x_g[e0 + 64]};

    v2f cAre, cAim, cBre, cBim, rootre, rootim;

    // 4 groups of 16 leaves; rolled to keep the dual-path body I$-resident.
#pragma clang loop unroll(disable)
    for (int q = 0; q < 4; ++q) {
        const int jq = 64 * s + 16 * q;    // leftmost leaf of this group
        v2f r2re[2], r2im[2];
        v2f h1re = vb(0.0f), h1im = vb(0.0f);
        v2f cre, cim;

#pragma unroll
        for (int p = 0; p < 4; ++p) {
            const int j = jq + 4 * p;
            // 4 leaves via scalar loads (wave-uniform address)
            const float* L = leaf_g + 2 * __builtin_amdgcn_readfirstlane(j);
            v2f l0 = vfma(vb(L[1]), x2, vb(L[0]));
            v2f l1 = vfma(vb(L[3]), x2, vb(L[2]));
            v2f l2 = vfma(vb(L[5]), x2, vb(L[4]));
            v2f l3 = vfma(vb(L[7]), x2, vb(L[6]));

            // round 0: nodes (j>>1), (j>>1)+1
            v2f Are, Aim, Bre, Bim;
            node_r0(l0, l1, x2, gptr(gate_g, j >> 1), Are, Aim);
            node_r0(l2, l3, x2, gptr(gate_g, (j >> 1) + 1), Bre, Bim);

            // round 1: node 512 + (j>>2)
            v2f r1re, r1im;
            node_any(Are, Aim, Bre, Bim, x2, gptr(gate_g, 512 + (j >> 2)), r1re, r1im);

            if (p & 1) {
                // round 2: node 768 + (j>>3)
                node_any(h1re, h1im, r1re, r1im, x2,
                         gptr(gate_g, 768 + (j >> 3)), r2re[p >> 1], r2im[p >> 1]);
            } else {
                h1re = r1re; h1im = r1im;
            }
        }
        // round 3: node 896 + (jq>>4)
        node_any(r2re[0], r2im[0], r2re[1], r2im[1], x2,
                 gptr(gate_g, 896 + (jq >> 4)), cre, cim);

        // rounds 4-5: static register merge (positions 4s+q at round 3)
        if (q == 0) {
            cAre = cre; cAim = cim;
        } else if (q == 1) {
            node_any(cAre, cAim, cre, cim, x2, gptr(gate_g, 960 + 2 * s), cBre, cBim);
        } else if (q == 2) {
            cAre = cre; cAim = cim;
        } else {
            v2f tre, tim;
            node_any(cAre, cAim, cre, cim, x2, gptr(gate_g, 961 + 2 * s), tre, tim);
            node_any(cBre, cBim, tre, tim, x2, gptr(gate_g, 992 + s), rootre, rootim);
        }
    }

    // round-5 subtree roots -> LDS
    s_t[s][lane] = make_float4(rootre.x, rootre.y, rootim.x, rootim.y);
    __syncthreads();

    // round 6: nodes 1008..1015, one per wave s<8
    if (s < 8) {
        float4 a = s_t[2 * s][lane], b = s_t[2 * s + 1][lane];
        v2f rre, rim;
        node_any((v2f){a.x, a.y}, (v2f){a.z, a.w}, (v2f){b.x, b.y}, (v2f){b.z, b.w},
                 x2, gptr(gate_g, 1008 + s), rre, rim);
        s_t[16 + s][lane] = make_float4(rre.x, rre.y, rim.x, rim.y);
    }
    __syncthreads();

    // round 7: nodes 1016..1019, waves s<4
    if (s < 4) {
        float4 a = s_t[16 + 2 * s][lane], b = s_t[17 + 2 * s][lane];
        v2f rre, rim;
        node_any((v2f){a.x, a.y}, (v2f){a.z, a.w}, (v2f){b.x, b.y}, (v2f){b.z, b.w},
                 x2, gptr(gate_g, 1016 + s), rre, rim);
        s_t[24 + s][lane] = make_float4(rre.x, rre.y, rim.x, rim.y);
    }
    __syncthreads();

    // round 8: nodes 1020, 1021, waves s<2
    if (s < 2) {
        float4 a = s_t[24 + 2 * s][lane], b = s_t[25 + 2 * s][lane];
        v2f rre, rim;
        node_any((v2f){a.x, a.y}, (v2f){a.z, a.w}, (v2f){b.x, b.y}, (v2f){b.z, b.w},
                 x2, gptr(gate_g, 1020 + s), rre, rim);
        s_t[28 + s][lane] = make_float4(rre.x, rre.y, rim.x, rim.y);
    }
    __syncthreads();

    // round 9: node 1022 -> output (wave 0)
    if (s == 0) {
        float4 a = s_t[28][lane], b = s_t[29][lane];
        v2f rre, rim;
        node_any((v2f){a.x, a.y}, (v2f){a.z, a.w}, (v2f){b.x, b.y}, (v2f){b.z, b.w},
                 x2, gptr(gate_g, 1022), rre, rim);
        if (out_real_only) {
            out[e0]      = rre.x;
            out[e0 + 64] = rre.y;
        } else {
            reinterpret_cast<float2*>(out)[e0]      = make_float2(rre.x, rim.x);
            reinterpret_cast<float2*>(out)[e0 + 64] = make_float2(rre.y, rim.y);
        }
    }
}

extern "C" void kernel_launch(void* const* d_in, const int* in_sizes, int n_in,
                              void* d_out, int out_size, void* d_ws, size_t ws_size,
                              hipStream_t stream) {
    const float* x    = (const float*)d_in[0];
    const float* leaf = (const float*)d_in[1];
    const float* gate = (const float*)d_in[2];
    float* out = (float*)d_out;
    const int batch = in_sizes[0];

    const int out_real_only = (out_size == batch) ? 1 : 0;

    dim3 block(64, 16);
    dim3 grid(batch / 128);
    hipLaunchKernelGGL(EMLTree1DLinear_kernel, grid, block, 0, stream,
                       x, leaf, gate, out, batch, out_real_only);
}